// Round 5
// baseline (167.187 us; speedup 1.0000x reference)
//
#include <hip/hip_runtime.h>

// Lovász-Softmax (B=1, C=3) — degenerate closed form (verified R1–R13, absmax=0):
//   loss = mean over present classes c of weight[c] * mean_{lab==c}(-log(softmax_c + 1e-8))
// R16 = R13 (1024 blk x 256 thr, GPT=6, two-kernel, simple loop) with
// NONTEMPORAL REMOVED — plain global loads. Single-variable A/B.
// Rationale: R12's counters show the kernel at 17% HBM with half the logical
// bytes served by L3, VALUBusy 12%, and ALL CU-side levers (grid 512/1024/2048,
// uniform 2-deep pipeline R14, per-stream phase skew R15) null. No pipe is
// saturated => suspect the nt streaming path itself (no-allocate / bypass
// fabric QoS), the one untested attribute common to every prior variant.
// err = log(e^za+e^zb+e^zc) - z_lab (R9-verified exact, absmax 0).

#define EPS 1e-8f
#define BLK 256
#define GPT 6          // float4 groups per thread
#define GPB (GPT*BLK)  // groups per block = 1536

typedef float fx4 __attribute__((ext_vector_type(4)));
typedef int   ix4 __attribute__((ext_vector_type(4)));

__device__ __forceinline__ void px_acc(float za, float zb, float zc, int la, int lb,
                                       float& s0, float& s1, float& s2,
                                       float& n0, float& n1, float& n2)
{
    float ea = __expf(za);
    float eb = __expf(zb);
    float ec = __expf(zc);
    float d  = ea + eb + ec;
    float zl = (la != 0) ? zb : ((lb != 0) ? zc : za);
    float err = __logf(d) - zl;          // == -log(softmax_lab), eps dropped
    float f1 = (la != 0) ? 1.f : 0.f;
    float f2 = (lb != 0) ? 1.f : 0.f;
    float f0 = 1.f - f1 - f2;
    s0 += f0 * err;  s1 += f1 * err;  s2 += f2 * err;
    n0 += f0;        n1 += f1;        n2 += f2;
}

__global__ __launch_bounds__(BLK) void lovasz_reduce_kernel(
    const float* __restrict__ probas,   // [3, P] channel-major
    const int*   __restrict__ labels,   // [3, P] one-hot int32
    float* __restrict__ partial,        // ws: [6][nblocks] transposed partials
    int P4, int P, int nfull, int nblocks)
{
    const fx4* z0 = (const fx4*)(probas);
    const fx4* z1 = (const fx4*)(probas + (size_t)P);
    const fx4* z2 = (const fx4*)(probas + 2 * (size_t)P);
    const ix4* l1 = (const ix4*)(labels + (size_t)P);
    const ix4* l2 = (const ix4*)(labels + 2 * (size_t)P);

    float s0 = 0.f, s1 = 0.f, s2 = 0.f;
    float n0 = 0.f, n1 = 0.f, n2 = 0.f;

    const int base = blockIdx.x * GPB + threadIdx.x;

    if (blockIdx.x < nfull) {
        #pragma unroll
        for (int j = 0; j < GPT; ++j) {
            int i = base + j * BLK;
            fx4 a = z0[i];
            fx4 b = z1[i];
            fx4 c = z2[i];
            ix4 u = l1[i];
            ix4 v = l2[i];
            px_acc(a.x, b.x, c.x, u.x, v.x, s0, s1, s2, n0, n1, n2);
            px_acc(a.y, b.y, c.y, u.y, v.y, s0, s1, s2, n0, n1, n2);
            px_acc(a.z, b.z, c.z, u.z, v.z, s0, s1, s2, n0, n1, n2);
            px_acc(a.w, b.w, c.w, u.w, v.w, s0, s1, s2, n0, n1, n2);
        }
    } else {
        #pragma unroll
        for (int j = 0; j < GPT; ++j) {
            int i = base + j * BLK;
            if (i < P4) {
                fx4 a = z0[i];
                fx4 b = z1[i];
                fx4 c = z2[i];
                ix4 u = l1[i];
                ix4 v = l2[i];
                px_acc(a.x, b.x, c.x, u.x, v.x, s0, s1, s2, n0, n1, n2);
                px_acc(a.y, b.y, c.y, u.y, v.y, s0, s1, s2, n0, n1, n2);
                px_acc(a.z, b.z, c.z, u.z, v.z, s0, s1, s2, n0, n1, n2);
                px_acc(a.w, b.w, c.w, u.w, v.w, s0, s1, s2, n0, n1, n2);
            }
        }
    }

    // wave (64-lane) shuffle reduction
    #pragma unroll
    for (int off = 32; off > 0; off >>= 1) {
        s0 += __shfl_down(s0, off);
        s1 += __shfl_down(s1, off);
        s2 += __shfl_down(s2, off);
        n0 += __shfl_down(n0, off);
        n1 += __shfl_down(n1, off);
        n2 += __shfl_down(n2, off);
    }

    __shared__ float red[6][4];
    int wave = threadIdx.x >> 6;
    int lane = threadIdx.x & 63;
    if (lane == 0) {
        red[0][wave] = s0; red[1][wave] = s1; red[2][wave] = s2;
        red[3][wave] = n0; red[4][wave] = n1; red[5][wave] = n2;
    }
    __syncthreads();
    if (threadIdx.x < 6) {
        int k = threadIdx.x;
        partial[(size_t)k * nblocks + blockIdx.x] =
            red[k][0] + red[k][1] + red[k][2] + red[k][3];
    }
}

__global__ __launch_bounds__(256) void lovasz_finalize_kernel(
    const float* __restrict__ partial, int nblocks,
    const float* __restrict__ probas, const int* __restrict__ labels,
    const float* __restrict__ weight, float* __restrict__ out,
    int P4, int P)
{
    float acc[6] = {0.f, 0.f, 0.f, 0.f, 0.f, 0.f};
    for (int b = threadIdx.x; b < nblocks; b += 256) {
        #pragma unroll
        for (int k = 0; k < 6; ++k)
            acc[k] += partial[(size_t)k * nblocks + b];
    }

    #pragma unroll
    for (int k = 0; k < 6; ++k)
        #pragma unroll
        for (int off = 32; off > 0; off >>= 1)
            acc[k] += __shfl_down(acc[k], off);

    __shared__ float red[6][4];
    int wave = threadIdx.x >> 6;
    int lane = threadIdx.x & 63;
    if (lane == 0) {
        #pragma unroll
        for (int k = 0; k < 6; ++k) red[k][wave] = acc[k];
    }
    __syncthreads();
    if (threadIdx.x == 0) {
        float s[6];
        #pragma unroll
        for (int k = 0; k < 6; ++k)
            s[k] = red[k][0] + red[k][1] + red[k][2] + red[k][3];
        // scalar tail (P % 4 != 0; empty for this shape)
        for (int i = 4 * P4; i < P; ++i) {
            px_acc(probas[i], probas[(size_t)P + i], probas[2 * (size_t)P + i],
                   labels[(size_t)P + i], labels[2 * (size_t)P + i],
                   s[0], s[1], s[2], s[3], s[4], s[5]);
        }
        float total = 0.f, cnt = 0.f;
        #pragma unroll
        for (int c = 0; c < 3; ++c) {
            if (s[3 + c] > 0.f) {
                total += weight[c] * s[c] / s[3 + c];
                cnt += 1.f;
            }
        }
        out[0] = (cnt > 0.f) ? total / cnt : 0.f;
    }
}

extern "C" void kernel_launch(void* const* d_in, const int* in_sizes, int n_in,
                              void* d_out, int out_size, void* d_ws, size_t ws_size,
                              hipStream_t stream) {
    const float* probas = (const float*)d_in[0];
    const float* weight = (const float*)d_in[1];
    const int*   labels = (const int*)d_in[2];
    float* partial = (float*)d_ws;

    int total = in_sizes[0];        // B*C*D*H*W with B=1, C=3
    int P  = total / 3;             // pixels = 6,291,456
    int P4 = P / 4;                 // 1,572,864 float4 groups
    int nfull = P4 / GPB;           // 1024 fully-covered blocks (4/CU)
    int rem = P4 - nfull * GPB;
    int nblocks = nfull + (rem ? 1 : 0);

    lovasz_reduce_kernel<<<nblocks, BLK, 0, stream>>>(probas, labels, partial,
                                                      P4, P, nfull, nblocks);
    lovasz_finalize_kernel<<<1, 256, 0, stream>>>(partial, nblocks, probas,
                                                  labels, weight, (float*)d_out,
                                                  P4, P);
}

// Round 7
// 153.956 us; speedup vs baseline: 1.0859x; 1.0859x over previous
//
#include <hip/hip_runtime.h>

// Lovász-Softmax (B=1, C=3) — degenerate closed form (verified R1–R16, absmax=0):
//   loss = mean over present classes c of weight[c] * mean_{lab==c}(-log(softmax_c + 1e-8))
// R17 (resubmit — prior round was an infra failure, not a kernel verdict)
// = R13 (1024 blk x 256 thr, GPT=6, two-kernel) + nt RESTORED (R16 A/B proved
// nt is +14 µs: plain loads thrash L1 — 5 streams ≡ 0 mod 32 KB, zero reuse)
// + FORCED load grouping: 15 named nt loads (5 streams × 3 iters) issued
// stream-major, then asm volatile memory clobber (loads cannot sink past it),
// then consume. R16's VGPR=32 showed the compiler keeps ~1 quintet in flight;
// three grids (512/1024/2048) all plateau ~3.6 TB/s => congestion-latency /
// insufficient enforced MLP is the last standing theory. This guarantees
// 15 KB in flight per wave (~240 KB/CU at 16 waves/CU).
// err = log(e^za+e^zb+e^zc) - z_lab (R9-verified exact, absmax 0).

#define EPS 1e-8f
#define BLK 256
#define GPT 6          // float4 groups per thread (2 batches of 3)
#define GPB (GPT*BLK)  // groups per block = 1536

typedef float fx4 __attribute__((ext_vector_type(4)));
typedef int   ix4 __attribute__((ext_vector_type(4)));

#define NTL(p) __builtin_nontemporal_load(p)

__device__ __forceinline__ void px_acc(float za, float zb, float zc, int la, int lb,
                                       float& s0, float& s1, float& s2,
                                       float& n0, float& n1, float& n2)
{
    float ea = __expf(za);
    float eb = __expf(zb);
    float ec = __expf(zc);
    float d  = ea + eb + ec;
    float zl = (la != 0) ? zb : ((lb != 0) ? zc : za);
    float err = __logf(d) - zl;          // == -log(softmax_lab), eps dropped
    float f1 = (la != 0) ? 1.f : 0.f;
    float f2 = (lb != 0) ? 1.f : 0.f;
    float f0 = 1.f - f1 - f2;
    s0 += f0 * err;  s1 += f1 * err;  s2 += f2 * err;
    n0 += f0;        n1 += f1;        n2 += f2;
}

__global__ __launch_bounds__(BLK) void lovasz_reduce_kernel(
    const float* __restrict__ probas,   // [3, P] channel-major
    const int*   __restrict__ labels,   // [3, P] one-hot int32
    float* __restrict__ partial,        // ws: [6][nblocks] transposed partials
    int P4, int P, int nfull, int nblocks)
{
    const fx4* z0 = (const fx4*)(probas);
    const fx4* z1 = (const fx4*)(probas + (size_t)P);
    const fx4* z2 = (const fx4*)(probas + 2 * (size_t)P);
    const ix4* l1 = (const ix4*)(labels + (size_t)P);
    const ix4* l2 = (const ix4*)(labels + 2 * (size_t)P);

    float s0 = 0.f, s1 = 0.f, s2 = 0.f;
    float n0 = 0.f, n1 = 0.f, n2 = 0.f;

    const int base = blockIdx.x * GPB + threadIdx.x;

    if (blockIdx.x < nfull) {
        #pragma unroll
        for (int g = 0; g < 2; ++g) {
            const int i0 = base + (3 * g + 0) * BLK;
            const int i1 = base + (3 * g + 1) * BLK;
            const int i2 = base + (3 * g + 2) * BLK;
            // ---- issue all 15 loads (stream-major: 3 KB sequential per stream) ----
            fx4 a0 = NTL(&z0[i0]);
            fx4 a1 = NTL(&z0[i1]);
            fx4 a2 = NTL(&z0[i2]);
            fx4 b0 = NTL(&z1[i0]);
            fx4 b1 = NTL(&z1[i1]);
            fx4 b2 = NTL(&z1[i2]);
            fx4 c0 = NTL(&z2[i0]);
            fx4 c1 = NTL(&z2[i1]);
            fx4 c2 = NTL(&z2[i2]);
            ix4 u0 = NTL(&l1[i0]);
            ix4 u1 = NTL(&l1[i1]);
            ix4 u2 = NTL(&l1[i2]);
            ix4 v0 = NTL(&l2[i0]);
            ix4 v1 = NTL(&l2[i1]);
            ix4 v2 = NTL(&l2[i2]);
            // loads may not sink past a memory clobber => all 15 in flight here
            asm volatile("" ::: "memory");
            // ---- consume in issue order (oldest first) ----
            px_acc(a0.x, b0.x, c0.x, u0.x, v0.x, s0, s1, s2, n0, n1, n2);
            px_acc(a0.y, b0.y, c0.y, u0.y, v0.y, s0, s1, s2, n0, n1, n2);
            px_acc(a0.z, b0.z, c0.z, u0.z, v0.z, s0, s1, s2, n0, n1, n2);
            px_acc(a0.w, b0.w, c0.w, u0.w, v0.w, s0, s1, s2, n0, n1, n2);
            px_acc(a1.x, b1.x, c1.x, u1.x, v1.x, s0, s1, s2, n0, n1, n2);
            px_acc(a1.y, b1.y, c1.y, u1.y, v1.y, s0, s1, s2, n0, n1, n2);
            px_acc(a1.z, b1.z, c1.z, u1.z, v1.z, s0, s1, s2, n0, n1, n2);
            px_acc(a1.w, b1.w, c1.w, u1.w, v1.w, s0, s1, s2, n0, n1, n2);
            px_acc(a2.x, b2.x, c2.x, u2.x, v2.x, s0, s1, s2, n0, n1, n2);
            px_acc(a2.y, b2.y, c2.y, u2.y, v2.y, s0, s1, s2, n0, n1, n2);
            px_acc(a2.z, b2.z, c2.z, u2.z, v2.z, s0, s1, s2, n0, n1, n2);
            px_acc(a2.w, b2.w, c2.w, u2.w, v2.w, s0, s1, s2, n0, n1, n2);
        }
    } else {
        #pragma unroll
        for (int j = 0; j < GPT; ++j) {
            int i = base + j * BLK;
            if (i < P4) {
                fx4 a = NTL(&z0[i]);
                fx4 b = NTL(&z1[i]);
                fx4 c = NTL(&z2[i]);
                ix4 u = NTL(&l1[i]);
                ix4 v = NTL(&l2[i]);
                px_acc(a.x, b.x, c.x, u.x, v.x, s0, s1, s2, n0, n1, n2);
                px_acc(a.y, b.y, c.y, u.y, v.y, s0, s1, s2, n0, n1, n2);
                px_acc(a.z, b.z, c.z, u.z, v.z, s0, s1, s2, n0, n1, n2);
                px_acc(a.w, b.w, c.w, u.w, v.w, s0, s1, s2, n0, n1, n2);
            }
        }
    }

    // wave (64-lane) shuffle reduction
    #pragma unroll
    for (int off = 32; off > 0; off >>= 1) {
        s0 += __shfl_down(s0, off);
        s1 += __shfl_down(s1, off);
        s2 += __shfl_down(s2, off);
        n0 += __shfl_down(n0, off);
        n1 += __shfl_down(n1, off);
        n2 += __shfl_down(n2, off);
    }

    __shared__ float red[6][4];
    int wave = threadIdx.x >> 6;
    int lane = threadIdx.x & 63;
    if (lane == 0) {
        red[0][wave] = s0; red[1][wave] = s1; red[2][wave] = s2;
        red[3][wave] = n0; red[4][wave] = n1; red[5][wave] = n2;
    }
    __syncthreads();
    if (threadIdx.x < 6) {
        int k = threadIdx.x;
        partial[(size_t)k * nblocks + blockIdx.x] =
            red[k][0] + red[k][1] + red[k][2] + red[k][3];
    }
}

__global__ __launch_bounds__(256) void lovasz_finalize_kernel(
    const float* __restrict__ partial, int nblocks,
    const float* __restrict__ probas, const int* __restrict__ labels,
    const float* __restrict__ weight, float* __restrict__ out,
    int P4, int P)
{
    float acc[6] = {0.f, 0.f, 0.f, 0.f, 0.f, 0.f};
    for (int b = threadIdx.x; b < nblocks; b += 256) {
        #pragma unroll
        for (int k = 0; k < 6; ++k)
            acc[k] += partial[(size_t)k * nblocks + b];
    }

    #pragma unroll
    for (int k = 0; k < 6; ++k)
        #pragma unroll
        for (int off = 32; off > 0; off >>= 1)
            acc[k] += __shfl_down(acc[k], off);

    __shared__ float red[6][4];
    int wave = threadIdx.x >> 6;
    int lane = threadIdx.x & 63;
    if (lane == 0) {
        #pragma unroll
        for (int k = 0; k < 6; ++k) red[k][wave] = acc[k];
    }
    __syncthreads();
    if (threadIdx.x == 0) {
        float s[6];
        #pragma unroll
        for (int k = 0; k < 6; ++k)
            s[k] = red[k][0] + red[k][1] + red[k][2] + red[k][3];
        // scalar tail (P % 4 != 0; empty for this shape)
        for (int i = 4 * P4; i < P; ++i) {
            px_acc(probas[i], probas[(size_t)P + i], probas[2 * (size_t)P + i],
                   labels[(size_t)P + i], labels[2 * (size_t)P + i],
                   s[0], s[1], s[2], s[3], s[4], s[5]);
        }
        float total = 0.f, cnt = 0.f;
        #pragma unroll
        for (int c = 0; c < 3; ++c) {
            if (s[3 + c] > 0.f) {
                total += weight[c] * s[c] / s[3 + c];
                cnt += 1.f;
            }
        }
        out[0] = (cnt > 0.f) ? total / cnt : 0.f;
    }
}

extern "C" void kernel_launch(void* const* d_in, const int* in_sizes, int n_in,
                              void* d_out, int out_size, void* d_ws, size_t ws_size,
                              hipStream_t stream) {
    const float* probas = (const float*)d_in[0];
    const float* weight = (const float*)d_in[1];
    const int*   labels = (const int*)d_in[2];
    float* partial = (float*)d_ws;

    int total = in_sizes[0];        // B*C*D*H*W with B=1, C=3
    int P  = total / 3;             // pixels = 6,291,456
    int P4 = P / 4;                 // 1,572,864 float4 groups
    int nfull = P4 / GPB;           // 1024 fully-covered blocks (4/CU)
    int rem = P4 - nfull * GPB;
    int nblocks = nfull + (rem ? 1 : 0);

    lovasz_reduce_kernel<<<nblocks, BLK, 0, stream>>>(probas, labels, partial,
                                                      P4, P, nfull, nblocks);
    lovasz_finalize_kernel<<<1, 256, 0, stream>>>(partial, nblocks, probas,
                                                  labels, weight, (float*)d_out,
                                                  P4, P);
}